// Round 8
// baseline (6211.069 us; speedup 1.0000x reference)
//
#include <hip/hip_runtime.h>
#include <stdint.h>

typedef _Float16 f16;
typedef _Float16 f16x8 __attribute__((ext_vector_type(8)));
typedef float f32x4 __attribute__((ext_vector_type(4)));

#define MFMA16(a, b, c) __builtin_amdgcn_mfma_f32_16x16x32_f16((a), (b), (c), 0, 0, 0)

// Sizes: B=64, S=512, I=512, H=1024, 4H=4096, O=64

// ---------------- prep kernels ----------------

// x (B,S,I) f32 -> x16 (S,B,I) f16; flat, 8 elems/thread
__global__ void k_conv_x(const float* __restrict__ x, f16* __restrict__ x16) {
  int i = blockIdx.x * 256 + threadIdx.x;   // 2,097,152 threads
  int o = i * 8;
  int s = o >> 15, b = (o >> 9) & 63, c = o & 511;
  const float* src = x + (size_t)b * 262144 + (size_t)s * 512 + c;
  float4 v0 = *(const float4*)(src);
  float4 v1 = *(const float4*)(src + 4);
  union { f16 h[8]; f16x8 v; } t;
  t.h[0] = (f16)v0.x; t.h[1] = (f16)v0.y; t.h[2] = (f16)v0.z; t.h[3] = (f16)v0.w;
  t.h[4] = (f16)v1.x; t.h[5] = (f16)v1.y; t.h[6] = (f16)v1.z; t.h[7] = (f16)v1.w;
  *(f16x8*)(x16 + o) = t.v;
}

// Weights -> per-(slab,wave,kk,colhalf) MFMA B-fragments, f32->f16.
// fid = ((jb*8 + w)*KK + kk)*2 + cf. Lane holds W[c][k..k+7]:
//   slab col c = cf*16 + (lane&15)  -> gate row g = (c>>3)*1024 + jb*8 + (c&7)
//   k = w*kPer + kk*32 + (lane>>4)*8
__global__ void k_conv_wfrag(const float* __restrict__ Wih, const float* __restrict__ Whh,
                             f16* __restrict__ Wf, int KI, int KK, int kPer) {
  int fid = blockIdx.x;
  int lane = threadIdx.x;
  int cf = fid & 1; int rest = fid >> 1;
  int kk = rest % KK; rest /= KK; int w = rest & 7; int jb = rest >> 3;
  int c = cf * 16 + (lane & 15);
  int g = (c >> 3) * 1024 + jb * 8 + (c & 7);
  int k = w * kPer + kk * 32 + ((lane >> 4) << 3);
  const float* src = (k < KI) ? (Wih + (size_t)g * KI + k)
                              : (Whh + (size_t)g * 1024 + (k - KI));
  union { f16 h[8]; f16x8 v; } t;
#pragma unroll
  for (int i = 0; i < 8; ++i) t.h[i] = (f16)src[i];
  *(f16x8*)(Wf + ((size_t)fid * 64 + lane) * 8) = t.v;
}

__global__ void k_conv_bias(const float* __restrict__ bih, const float* __restrict__ bhh,
                            float* __restrict__ br) {
  int d = blockIdx.x * 64 + threadIdx.x;  // 4096
  int jb = d >> 5, r = d & 31;
  int g = (r >> 3) * 1024 + jb * 8 + (r & 7);
  br[d] = bih[g] + bhh[g];
}

__global__ void k_conv_wfc(const float* __restrict__ Wfc, f16* __restrict__ Wfc16) {
  int i = blockIdx.x * 256 + threadIdx.x;
  Wfc16[i] = (f16)Wfc[i];
}

// ---------------- persistent pipelined LSTM ----------------
// 256 blocks x 512 threads, cooperative. Blocks 0..127: layer0 slab jb,
// 128..255: layer1 slab jb. Weights in VGPRs. h-operand reads: coalesced
// global_load_dwordx4 sc0 sc1 (LLC-coherent), counted-vmcnt pipeline.
// Sync: contiguous flag arrays flags[layer*128+jb] (512B/layer); wave 0
// polls all 256 flags with ONE asm block of 4 coalesced lane-parallel
// sc0sc1 dword loads. No hierarchy (removes 2 LLC RTs from the recurrence
// cycle), no fences anywhere.
__global__ __launch_bounds__(512, 2)
void k_persist(const f16* __restrict__ x16,
               const f16* __restrict__ W0f, const float* __restrict__ b0r,
               const f16* __restrict__ W1f, const float* __restrict__ b1r,
               f16* __restrict__ h0buf, f16* __restrict__ h1buf,
               f16* __restrict__ h1all, int* flags) {
  const int layer = blockIdx.x >> 7;
  const int jb = blockIdx.x & 127;

  __shared__ float cred[8][64][36];  // stride 36: write 2-way, gate-read 2-way

  int* myflag = flags + layer * 128 + jb;

  const int tid = threadIdx.x;
  const int w = tid >> 6, lane = tid & 63;
  const int l15 = lane & 15, q8 = (lane >> 4) << 3;
  const int m = tid >> 3, jl = tid & 7, jg = jb * 8 + jl;

  const float* bias = (layer ? b1r : b0r) + jb * 32;
  const float bI = bias[jl], bF = bias[8 + jl], bG = bias[16 + jl], bO = bias[24 + jl];
  float creg = 0.f;

  const int* pf0a = flags + lane;
  const int* pf0b = flags + 64 + lane;
  const int* pf1a = flags + 128 + lane;
  const int* pf1b = flags + 192 + lane;

#define POLLG(n0v, n1v)                                                                  \
  {                                                                                      \
    if (w == 0) {                                                                        \
      int n0 = (n0v), n1 = (n1v);                                                        \
      for (;;) {                                                                         \
        int a_, b_, c_, d_;                                                              \
        asm volatile(                                                                    \
            "global_load_dword %0, %4, off sc0 sc1\n\t"                                  \
            "global_load_dword %1, %5, off sc0 sc1\n\t"                                  \
            "global_load_dword %2, %6, off sc0 sc1\n\t"                                  \
            "global_load_dword %3, %7, off sc0 sc1\n\t"                                  \
            "s_waitcnt vmcnt(0)"                                                         \
            : "=&v"(a_), "=&v"(b_), "=&v"(c_), "=&v"(d_)                                 \
            : "v"(pf0a), "v"(pf0b), "v"(pf1a), "v"(pf1b)                                 \
            : "memory");                                                                 \
        if (__all((a_ >= n0) && (b_ >= n0) && (c_ >= n1) && (d_ >= n1))) break;          \
        __builtin_amdgcn_s_sleep(1);                                                     \
      }                                                                                  \
    }                                                                                    \
    __syncthreads();                                                                     \
  }

#define CRED_AND_POINTWISE(HOUT, HALL)                                                   \
  {                                                                                      \
    _Pragma("unroll") for (int rf = 0; rf < 4; ++rf)                                     \
      _Pragma("unroll") for (int cf = 0; cf < 2; ++cf)                                   \
        _Pragma("unroll") for (int r = 0; r < 4; ++r)                                    \
          cred[w][rf * 16 + (lane >> 4) * 4 + r][cf * 16 + l15] = acc[rf][cf][r];        \
    __syncthreads();                                                                     \
    float ip = bI, fp = bF, gp2 = bG, op = bO;                                           \
    _Pragma("unroll") for (int ww = 0; ww < 8; ++ww) {                                   \
      ip += cred[ww][m][jl];                                                             \
      fp += cred[ww][m][8 + jl];                                                         \
      gp2 += cred[ww][m][16 + jl];                                                       \
      op += cred[ww][m][24 + jl];                                                        \
    }                                                                                    \
    float ig = 1.f / (1.f + __expf(-ip));                                                \
    float fg = 1.f / (1.f + __expf(-fp));                                                \
    float ea = __expf(-2.f * fabsf(gp2));                                                \
    float gg = copysignf((1.f - ea) / (1.f + ea), gp2);                                  \
    float og = 1.f / (1.f + __expf(-op));                                                \
    creg = fg * creg + ig * gg;                                                          \
    float eb = __expf(-2.f * fabsf(creg));                                               \
    float hval = og * copysignf((1.f - eb) / (1.f + eb), creg);                          \
    size_t idx = (size_t)m * 1024 + jg;                                                  \
    union { f16 h; unsigned short s; } cv; cv.h = (f16)hval;                             \
    __hip_atomic_store((unsigned short*)((HOUT) + idx), cv.s,                            \
                       __ATOMIC_RELAXED, __HIP_MEMORY_SCOPE_AGENT);                      \
    if (HALL) ((f16*)(HALL))[idx] = cv.h;                                                \
    __syncthreads(); /* drains vmcnt(0): h stores ack'd at LLC */                        \
    if (tid == 0)                                                                        \
      __hip_atomic_store(myflag, t + 1, __ATOMIC_RELAXED, __HIP_MEMORY_SCOPE_AGENT);     \
  }

// coalesced LLC-coherent load (bypass L1+L2) / cached load, both vmcnt-counted
#define GLD_X(dst, addr)                                                                 \
  asm volatile("global_load_dwordx4 %0, %1, off sc0 sc1" : "=&v"(dst) : "v"(addr) : "memory")
#define GLD_C(dst, addr)                                                                 \
  asm volatile("global_load_dwordx4 %0, %1, off" : "=&v"(dst) : "v"(addr) : "memory")
#define WAITV(n)                                                                         \
  { asm volatile("s_waitcnt vmcnt(" #n ")" ::: "memory"); __builtin_amdgcn_sched_barrier(0); }

  if (layer == 0) {
    const int KK = 6;  // kPer = 192, Ktot = 1536
    f16x8 wreg[6][2];
#pragma unroll
    for (int kk = 0; kk < KK; ++kk)
#pragma unroll
      for (int cf = 0; cf < 2; ++cf)
        wreg[kk][cf] = *(const f16x8*)(W0f + ((size_t)((jb * 8 + w) * KK + kk) * 2 + cf) * 512 + lane * 8);
#pragma unroll
    for (int kk = 0; kk < KK; ++kk)
      asm volatile("" : "+v"(wreg[kk][0]), "+v"(wreg[kk][1]));

    const int kbeg = w * 192;
    for (int t = 0; t < 512; ++t) {
      const f16* A0 = x16 + (size_t)t * 32768;
      const f16* A1 = h0buf + (size_t)((t + 3) & 3) * 65536;  // h0_{t-1}
      f16* hout = h0buf + (size_t)(t & 3) * 65536;            // h0_t

      f16x8 af[4][4];
#define ISSUE0(kk)                                                                       \
      {                                                                                  \
        int k_ = kbeg + (kk) * 32 + q8;                                                  \
        if (k_ < 512) {                                                                  \
          const f16* ap_ = A0 + k_;                                                      \
          _Pragma("unroll") for (int rf = 0; rf < 4; ++rf)                               \
            GLD_C(af[(kk) & 3][rf], ap_ + (size_t)(rf * 16 + l15) * 512);                \
        } else {                                                                         \
          const f16* ap_ = A1 + (k_ - 512);                                              \
          _Pragma("unroll") for (int rf = 0; rf < 4; ++rf)                               \
            GLD_X(af[(kk) & 3][rf], ap_ + (size_t)(rf * 16 + l15) * 1024);               \
        }                                                                                \
      }
#define MF0(kk)                                                                          \
      { _Pragma("unroll") for (int rf = 0; rf < 4; ++rf) {                               \
          acc[rf][0] = MFMA16(af[(kk) & 3][rf], wreg[kk][0], acc[rf][0]);                \
          acc[rf][1] = MFMA16(af[(kk) & 3][rf], wreg[kk][1], acc[rf][1]); } }

      f32x4 acc[4][2];
#pragma unroll
      for (int i = 0; i < 4; ++i) {
        acc[i][0] = f32x4{0.f, 0.f, 0.f, 0.f};
        acc[i][1] = f32x4{0.f, 0.f, 0.f, 0.f};
      }

      // waves 0-2: kk0-3 are pure-x (flag-independent) -> prefetch before poll
      if (w <= 2) { ISSUE0(0) ISSUE0(1) ISSUE0(2) ISSUE0(3) }
      POLLG(t, t - 3);
      if (w > 2) { ISSUE0(0) ISSUE0(1) ISSUE0(2) ISSUE0(3) }
      WAITV(12) MF0(0) ISSUE0(4)
      WAITV(12) MF0(1) ISSUE0(5)
      WAITV(12) MF0(2)
      WAITV(8)  MF0(3)
      WAITV(4)  MF0(4)
      WAITV(0)  MF0(5)
#undef ISSUE0
#undef MF0

      CRED_AND_POINTWISE(hout, (f16*)nullptr);
    }
  } else {
    const int KK = 8;  // kPer = 256, Ktot = 2048
    f16x8 wreg[8][2];
#pragma unroll
    for (int kk = 0; kk < KK; ++kk)
#pragma unroll
      for (int cf = 0; cf < 2; ++cf)
        wreg[kk][cf] = *(const f16x8*)(W1f + ((size_t)((jb * 8 + w) * KK + kk) * 2 + cf) * 512 + lane * 8);
#pragma unroll
    for (int kk = 0; kk < KK; ++kk)
      asm volatile("" : "+v"(wreg[kk][0]), "+v"(wreg[kk][1]));

    const int kbeg = w * 256;
    for (int t = 0; t < 512; ++t) {
      const f16* A0 = h0buf + (size_t)(t & 3) * 65536;        // h0_t
      const f16* A1 = h1buf + (size_t)((t + 3) & 3) * 65536;  // h1_{t-1}
      f16* hout = h1buf + (size_t)(t & 3) * 65536;            // h1_t
      f16* hall = h1all + (size_t)t * 65536;

      POLLG(t + 1, t);

      f16x8 af[4][4];
#define ISSUE1(kk)                                                                       \
      {                                                                                  \
        int k_ = kbeg + (kk) * 32 + q8;                                                  \
        const f16* ap_ = (k_ < 1024) ? (A0 + k_) : (A1 + (k_ - 1024));                   \
        _Pragma("unroll") for (int rf = 0; rf < 4; ++rf)                                 \
          GLD_X(af[(kk) & 3][rf], ap_ + (size_t)(rf * 16 + l15) * 1024);                 \
      }
#define MF1(kk)                                                                          \
      { _Pragma("unroll") for (int rf = 0; rf < 4; ++rf) {                               \
          acc[rf][0] = MFMA16(af[(kk) & 3][rf], wreg[kk][0], acc[rf][0]);                \
          acc[rf][1] = MFMA16(af[(kk) & 3][rf], wreg[kk][1], acc[rf][1]); } }

      f32x4 acc[4][2];
#pragma unroll
      for (int i = 0; i < 4; ++i) {
        acc[i][0] = f32x4{0.f, 0.f, 0.f, 0.f};
        acc[i][1] = f32x4{0.f, 0.f, 0.f, 0.f};
      }

      ISSUE1(0) ISSUE1(1) ISSUE1(2) ISSUE1(3)
      WAITV(12) MF1(0) ISSUE1(4)
      WAITV(12) MF1(1) ISSUE1(5)
      WAITV(12) MF1(2) ISSUE1(6)
      WAITV(12) MF1(3) ISSUE1(7)
      WAITV(12) MF1(4)
      WAITV(8)  MF1(5)
      WAITV(4)  MF1(6)
      WAITV(0)  MF1(7)
#undef ISSUE1
#undef MF1

      CRED_AND_POINTWISE(hout, hall);
    }
  }
#undef POLLG
#undef CRED_AND_POINTWISE
#undef GLD_X
#undef GLD_C
#undef WAITV
}

// ---------------- final FC ----------------
__global__ __launch_bounds__(512, 1)
void k_fc(const f16* __restrict__ h1all, const f16* __restrict__ Wfc16,
          const float* __restrict__ bfc, float* __restrict__ out) {
  const int s = blockIdx.x;
  const f16* A = h1all + (size_t)s * 65536;
  __shared__ float credf[8][64][68];

  const int w = threadIdx.x >> 6;
  const int lane = threadIdx.x & 63;
  const int l15 = lane & 15;
  const int ksub = (lane >> 4) << 3;

  f32x4 acc[4][4];
#pragma unroll
  for (int i = 0; i < 4; ++i)
#pragma unroll
    for (int j = 0; j < 4; ++j) acc[i][j] = f32x4{0.f, 0.f, 0.f, 0.f};

  const int kbeg = w * 128, kend = kbeg + 128;
  f16x8 af0[4], bf0[4], af1[4], bf1[4];

  auto LOADK = [&](int kc, f16x8(&a)[4], f16x8(&b)[4]) {
    const f16* ap = A + kc + ksub;
#pragma unroll
    for (int rf = 0; rf < 4; ++rf)
      a[rf] = *(const f16x8*)(ap + (size_t)(rf * 16 + l15) * 1024);
    const f16* bp = Wfc16 + kc + ksub;
#pragma unroll
    for (int cf = 0; cf < 4; ++cf)
      b[cf] = *(const f16x8*)(bp + (size_t)(cf * 16 + l15) * 1024);
  };

  LOADK(kbeg, af0, bf0);
  for (int kc = kbeg; kc < kend; kc += 64) {
    LOADK(kc + 32, af1, bf1);
#pragma unroll
    for (int rf = 0; rf < 4; ++rf)
#pragma unroll
      for (int cf = 0; cf < 4; ++cf) acc[rf][cf] = MFMA16(af0[rf], bf0[cf], acc[rf][cf]);
    if (kc + 64 < kend) LOADK(kc + 64, af0, bf0);
#pragma unroll
    for (int rf = 0; rf < 4; ++rf)
#pragma unroll
      for (int cf = 0; cf < 4; ++cf) acc[rf][cf] = MFMA16(af1[rf], bf1[cf], acc[rf][cf]);
  }

#pragma unroll
  for (int rf = 0; rf < 4; ++rf)
#pragma unroll
    for (int cf = 0; cf < 4; ++cf)
#pragma unroll
      for (int r = 0; r < 4; ++r)
        credf[w][rf * 16 + (lane >> 4) * 4 + r][cf * 16 + l15] = acc[rf][cf][r];

  __syncthreads();

  int m = threadIdx.x >> 3;
  int cbase = (threadIdx.x & 7) * 8;
#pragma unroll
  for (int u = 0; u < 8; ++u) {
    int col = cbase + u;
    float v = bfc[col];
#pragma unroll
    for (int ww = 0; ww < 8; ++ww) v += credf[ww][m][col];
    out[((size_t)m * 512 + s) * 64 + col] = v;
  }
}

// ---------------- host ----------------
extern "C" void kernel_launch(void* const* d_in, const int* in_sizes, int n_in,
                              void* d_out, int out_size, void* d_ws, size_t ws_size,
                              hipStream_t stream) {
  const float* x    = (const float*)d_in[0];
  const float* Wih0 = (const float*)d_in[1];
  const float* Whh0 = (const float*)d_in[2];
  const float* bih0 = (const float*)d_in[3];
  const float* bhh0 = (const float*)d_in[4];
  const float* Wih1 = (const float*)d_in[5];
  const float* Whh1 = (const float*)d_in[6];
  const float* bih1 = (const float*)d_in[7];
  const float* bhh1 = (const float*)d_in[8];
  const float* Wfc  = (const float*)d_in[9];
  const float* bfc  = (const float*)d_in[10];
  float* out = (float*)d_out;

  char* ws = (char*)d_ws;
  f16*   W0f   = (f16*)(ws + 0);           // 12288 frags * 1KB = 12,582,912
  f16*   W1f   = (f16*)(ws + 12582912);    // 16384 frags * 1KB = 16,777,216
  f16*   Wfc16 = (f16*)(ws + 29360128);    // 131,072
  float* b0r   = (float*)(ws + 29491200);  // 16,384
  float* b1r   = (float*)(ws + 29507584);  // 16,384
  f16*   x16   = (f16*)(ws + 29523968);    // 33,554,432
  f16*   h1all = (f16*)(ws + 63078400);    // 67,108,864
  f16*   h0buf = (f16*)(ws + 130187264);   // 4 * 131,072 = 524,288
  f16*   h1buf = (f16*)(ws + 130711552);   // 524,288
  int*   flags = (int*)(ws + 131235840);   // 1,024 (2 layers * 128 ints contiguous)

  k_conv_x<<<8192, 256, 0, stream>>>(x, x16);
  k_conv_wfrag<<<12288, 64, 0, stream>>>(Wih0, Whh0, W0f, 512, 6, 192);
  k_conv_wfrag<<<16384, 64, 0, stream>>>(Wih1, Whh1, W1f, 1024, 8, 256);
  k_conv_bias<<<64, 64, 0, stream>>>(bih0, bhh0, b0r);
  k_conv_bias<<<64, 64, 0, stream>>>(bih1, bhh1, b1r);
  k_conv_wfc<<<256, 256, 0, stream>>>(Wfc, Wfc16);
  // zero h ring buffers + flags every launch (graph-replay determinism)
  hipMemsetAsync(ws + 130187264, 0, 524288 * 2 + 1024, stream);

  {
    const f16* x16c = x16; const f16* W0fc = W0f; const float* b0rc = b0r;
    const f16* W1fc = W1f; const float* b1rc = b1r;
    f16 *p0 = h0buf, *p1 = h1buf, *ph = h1all;
    int* fl = flags;
    void* kargs[] = { &x16c, &W0fc, &b0rc, &W1fc, &b1rc, &p0, &p1, &ph, &fl };
    hipLaunchCooperativeKernel((void*)k_persist, dim3(256), dim3(512), kargs, 0, stream);
  }

  k_fc<<<512, 512, 0, stream>>>(h1all, Wfc16, bfc, out);
}

// Round 9
// 5753.834 us; speedup vs baseline: 1.0795x; 1.0795x over previous
//
#include <hip/hip_runtime.h>
#include <stdint.h>

typedef _Float16 f16;
typedef _Float16 f16x8 __attribute__((ext_vector_type(8)));
typedef float f32x4 __attribute__((ext_vector_type(4)));

#define MFMA16(a, b, c) __builtin_amdgcn_mfma_f32_16x16x32_f16((a), (b), (c), 0, 0, 0)

// Sizes: B=64, S=512, I=512, H=1024, 4H=4096, O=64

// ---------------- prep kernels ----------------

__global__ void k_conv_x(const float* __restrict__ x, f16* __restrict__ x16) {
  int i = blockIdx.x * 256 + threadIdx.x;
  int o = i * 8;
  int s = o >> 15, b = (o >> 9) & 63, c = o & 511;
  const float* src = x + (size_t)b * 262144 + (size_t)s * 512 + c;
  float4 v0 = *(const float4*)(src);
  float4 v1 = *(const float4*)(src + 4);
  union { f16 h[8]; f16x8 v; } t;
  t.h[0] = (f16)v0.x; t.h[1] = (f16)v0.y; t.h[2] = (f16)v0.z; t.h[3] = (f16)v0.w;
  t.h[4] = (f16)v1.x; t.h[5] = (f16)v1.y; t.h[6] = (f16)v1.z; t.h[7] = (f16)v1.w;
  *(f16x8*)(x16 + o) = t.v;
}

// Weights -> per-(slab,wave,kk,colhalf) MFMA B-fragments, f32->f16.
__global__ void k_conv_wfrag(const float* __restrict__ Wih, const float* __restrict__ Whh,
                             f16* __restrict__ Wf, int KI, int KK, int kPer) {
  int fid = blockIdx.x;
  int lane = threadIdx.x;
  int cf = fid & 1; int rest = fid >> 1;
  int kk = rest % KK; rest /= KK; int w = rest & 7; int jb = rest >> 3;
  int c = cf * 16 + (lane & 15);
  int g = (c >> 3) * 1024 + jb * 8 + (c & 7);
  int k = w * kPer + kk * 32 + ((lane >> 4) << 3);
  const float* src = (k < KI) ? (Wih + (size_t)g * KI + k)
                              : (Whh + (size_t)g * 1024 + (k - KI));
  union { f16 h[8]; f16x8 v; } t;
#pragma unroll
  for (int i = 0; i < 8; ++i) t.h[i] = (f16)src[i];
  *(f16x8*)(Wf + ((size_t)fid * 64 + lane) * 8) = t.v;
}

__global__ void k_conv_bias(const float* __restrict__ bih, const float* __restrict__ bhh,
                            float* __restrict__ br) {
  int d = blockIdx.x * 64 + threadIdx.x;
  int jb = d >> 5, r = d & 31;
  int g = (r >> 3) * 1024 + jb * 8 + (r & 7);
  br[d] = bih[g] + bhh[g];
}

__global__ void k_conv_wfc(const float* __restrict__ Wfc, f16* __restrict__ Wfc16) {
  int i = blockIdx.x * 256 + threadIdx.x;
  Wfc16[i] = (f16)Wfc[i];
}

// ---------------- persistent pipelined LSTM ----------------
// 256 blocks x 512 threads, cooperative. Blocks 0..127: layer0 slab jb,
// 128..255: layer1 slab jb. Weights in VGPRs.
// H0C=1: h0/h1 stored in depth-(512+1) rings (unique address per step), so
// consumer reads are PLAIN CACHED loads (L2 can never hold a stale copy:
// address untouched before the producer's write-through store) -> 16
// blocks/XCD share one LLC fetch; broadcast traffic served from L2.
// H0C=0 (small-ws fallback): h0 = 4-deep ring with sc0sc1 bypass reads +
// WAR poll term; h1 still cached (its ring is h1all, naturally depth-512).
// Sync = round-7 hierarchical scheme (empirically best): per-block flags on
// 128B lines; blocks jb<8 aggregate 16 flags -> one 64B gflag line; wave 0
// polls that single line. No fences anywhere.
template <int H0C>
__global__ __launch_bounds__(512, 2)
void k_persist(const f16* __restrict__ x16,
               const f16* __restrict__ W0f, const float* __restrict__ b0r,
               const f16* __restrict__ W1f, const float* __restrict__ b1r,
               f16* __restrict__ h0ring, f16* __restrict__ h1ring,
               int* flags, int* gflags) {
  const int layer = blockIdx.x >> 7;
  const int jb = blockIdx.x & 127;

  __shared__ float cred[8][64][36];

  int* flag0 = flags;          // 128 flags, 128B apart
  int* flag1 = flags + 4096;
  int* myflag = (layer ? flag1 : flag0) + jb * 32;

  const int tid = threadIdx.x;
  const int w = tid >> 6, lane = tid & 63;
  const int l15 = lane & 15, q8 = (lane >> 4) << 3;
  const int m = tid >> 3, jl = tid & 7, jg = jb * 8 + jl;

  const float* bias = (layer ? b1r : b0r) + jb * 32;
  const float bI = bias[jl], bF = bias[8 + jl], bG = bias[16 + jl], bO = bias[24 + jl];
  float creg = 0.f;

  const int* gp = gflags + l15;         // lanes 0-7: layer0 groups, 8-15: layer1
  const bool isg1 = l15 >= 8;
  const int* aggp = (layer ? flag1 : flag0) + (jb * 16 + l15) * 32;
  int* myg = gflags + (layer ? 8 : 0) + jb;

#define POLLG(n0v, n1v)                                                                  \
  {                                                                                      \
    int need_ = isg1 ? (n1v) : (n0v);                                                    \
    if (w == 0) {                                                                        \
      for (;;) {                                                                         \
        int v_ = __hip_atomic_load(gp, __ATOMIC_RELAXED, __HIP_MEMORY_SCOPE_AGENT);      \
        if (__all(v_ >= need_)) break;                                                   \
        __builtin_amdgcn_s_sleep(1);                                                     \
      }                                                                                  \
    }                                                                                    \
    __syncthreads();                                                                     \
  }

#define CRED_AND_POINTWISE(HOUT)                                                         \
  {                                                                                      \
    _Pragma("unroll") for (int rf = 0; rf < 4; ++rf)                                     \
      _Pragma("unroll") for (int cf = 0; cf < 2; ++cf)                                   \
        _Pragma("unroll") for (int r = 0; r < 4; ++r)                                    \
          cred[w][rf * 16 + (lane >> 4) * 4 + r][cf * 16 + l15] = acc[rf][cf][r];        \
    __syncthreads();                                                                     \
    float ip = bI, fp = bF, gp2 = bG, op = bO;                                           \
    _Pragma("unroll") for (int ww = 0; ww < 8; ++ww) {                                   \
      ip += cred[ww][m][jl];                                                             \
      fp += cred[ww][m][8 + jl];                                                         \
      gp2 += cred[ww][m][16 + jl];                                                       \
      op += cred[ww][m][24 + jl];                                                        \
    }                                                                                    \
    float ig = 1.f / (1.f + __expf(-ip));                                                \
    float fg = 1.f / (1.f + __expf(-fp));                                                \
    float ea = __expf(-2.f * fabsf(gp2));                                                \
    float gg = copysignf((1.f - ea) / (1.f + ea), gp2);                                  \
    float og = 1.f / (1.f + __expf(-op));                                                \
    creg = fg * creg + ig * gg;                                                          \
    float eb = __expf(-2.f * fabsf(creg));                                               \
    float hval = og * copysignf((1.f - eb) / (1.f + eb), creg);                          \
    size_t idx = (size_t)m * 1024 + jg;                                                  \
    union { f16 h; unsigned short s; } cv; cv.h = (f16)hval;                             \
    __hip_atomic_store((unsigned short*)((HOUT) + idx), cv.s,                            \
                       __ATOMIC_RELAXED, __HIP_MEMORY_SCOPE_AGENT);                      \
    __syncthreads(); /* drains vmcnt(0): h store ack'd at LLC */                         \
    if (tid == 0)                                                                        \
      __hip_atomic_store(myflag, t + 1, __ATOMIC_RELAXED, __HIP_MEMORY_SCOPE_AGENT);     \
    if (jb < 8 && w == 0) {                                                              \
      for (;;) {                                                                         \
        int v_ = __hip_atomic_load(aggp, __ATOMIC_RELAXED, __HIP_MEMORY_SCOPE_AGENT);    \
        if (__all(v_ >= t + 1)) break;                                                   \
        __builtin_amdgcn_s_sleep(1);                                                     \
      }                                                                                  \
      if (lane == 0)                                                                     \
        __hip_atomic_store(myg, t + 1, __ATOMIC_RELAXED, __HIP_MEMORY_SCOPE_AGENT);      \
    }                                                                                    \
  }

#define GLD_X(dst, addr)                                                                 \
  asm volatile("global_load_dwordx4 %0, %1, off sc0 sc1" : "=&v"(dst) : "v"(addr) : "memory")
#define GLD_C(dst, addr)                                                                 \
  asm volatile("global_load_dwordx4 %0, %1, off" : "=&v"(dst) : "v"(addr) : "memory")
#define WAITV(n)                                                                         \
  { asm volatile("s_waitcnt vmcnt(" #n ")" ::: "memory"); __builtin_amdgcn_sched_barrier(0); }

  if (layer == 0) {
    const int KK = 6;  // kPer = 192, Ktot = 1536
    f16x8 wreg[6][2];
#pragma unroll
    for (int kk = 0; kk < KK; ++kk)
#pragma unroll
      for (int cf = 0; cf < 2; ++cf)
        wreg[kk][cf] = *(const f16x8*)(W0f + ((size_t)((jb * 8 + w) * KK + kk) * 2 + cf) * 512 + lane * 8);
#pragma unroll
    for (int kk = 0; kk < KK; ++kk)
      asm volatile("" : "+v"(wreg[kk][0]), "+v"(wreg[kk][1]));

    const int kbeg = w * 192;
    for (int t = 0; t < 512; ++t) {
      const f16* A0x = x16 + (size_t)t * 32768;
      const f16* A1h = H0C ? (h0ring + (size_t)t * 65536)              // h0_{t-1}
                           : (h0ring + (size_t)((t + 3) & 3) * 65536);
      f16* hout = H0C ? (h0ring + (size_t)(t + 1) * 65536)             // h0_t
                      : (h0ring + (size_t)(t & 3) * 65536);

      POLLG(t, H0C ? 0 : (t - 3));

      f16x8 af[4][4];
#define ISSUE0(kk)                                                                       \
      {                                                                                  \
        int k_ = kbeg + (kk) * 32 + q8;                                                  \
        if (k_ < 512) {                                                                  \
          const f16* ap_ = A0x + k_;                                                     \
          _Pragma("unroll") for (int rf = 0; rf < 4; ++rf)                               \
            GLD_C(af[(kk) & 3][rf], ap_ + (size_t)(rf * 16 + l15) * 512);                \
        } else {                                                                         \
          const f16* ap_ = A1h + (k_ - 512);                                             \
          _Pragma("unroll") for (int rf = 0; rf < 4; ++rf) {                             \
            if (H0C) { GLD_C(af[(kk) & 3][rf], ap_ + (size_t)(rf * 16 + l15) * 1024); }  \
            else     { GLD_X(af[(kk) & 3][rf], ap_ + (size_t)(rf * 16 + l15) * 1024); }  \
          }                                                                              \
        }                                                                                \
      }
#define MF0(kk)                                                                          \
      { _Pragma("unroll") for (int rf = 0; rf < 4; ++rf) {                               \
          acc[rf][0] = MFMA16(af[(kk) & 3][rf], wreg[kk][0], acc[rf][0]);                \
          acc[rf][1] = MFMA16(af[(kk) & 3][rf], wreg[kk][1], acc[rf][1]); } }

      f32x4 acc[4][2];
#pragma unroll
      for (int i = 0; i < 4; ++i) {
        acc[i][0] = f32x4{0.f, 0.f, 0.f, 0.f};
        acc[i][1] = f32x4{0.f, 0.f, 0.f, 0.f};
      }

      ISSUE0(0) ISSUE0(1) ISSUE0(2) ISSUE0(3)
      WAITV(12) MF0(0) ISSUE0(4)
      WAITV(12) MF0(1) ISSUE0(5)
      WAITV(12) MF0(2)
      WAITV(8)  MF0(3)
      WAITV(4)  MF0(4)
      WAITV(0)  MF0(5)
#undef ISSUE0
#undef MF0

      CRED_AND_POINTWISE(hout);
    }
  } else {
    const int KK = 8;  // kPer = 256, Ktot = 2048
    f16x8 wreg[8][2];
#pragma unroll
    for (int kk = 0; kk < KK; ++kk)
#pragma unroll
      for (int cf = 0; cf < 2; ++cf)
        wreg[kk][cf] = *(const f16x8*)(W1f + ((size_t)((jb * 8 + w) * KK + kk) * 2 + cf) * 512 + lane * 8);
#pragma unroll
    for (int kk = 0; kk < KK; ++kk)
      asm volatile("" : "+v"(wreg[kk][0]), "+v"(wreg[kk][1]));

    const int kbeg = w * 256;
    for (int t = 0; t < 512; ++t) {
      const f16* A0 = H0C ? (h0ring + (size_t)(t + 1) * 65536)         // h0_t
                          : (h0ring + (size_t)(t & 3) * 65536);
      const f16* A1 = h1ring + (size_t)t * 65536;                      // h1_{t-1}, cached
      f16* hout = h1ring + (size_t)(t + 1) * 65536;                    // h1_t (= h1all slot)

      POLLG(t + 1, t);

      f16x8 af[4][4];
#define ISSUE1(kk)                                                                       \
      {                                                                                  \
        int k_ = kbeg + (kk) * 32 + q8;                                                  \
        if (k_ < 1024) {                                                                 \
          const f16* ap_ = A0 + k_;                                                      \
          _Pragma("unroll") for (int rf = 0; rf < 4; ++rf) {                             \
            if (H0C) { GLD_C(af[(kk) & 3][rf], ap_ + (size_t)(rf * 16 + l15) * 1024); }  \
            else     { GLD_X(af[(kk) & 3][rf], ap_ + (size_t)(rf * 16 + l15) * 1024); }  \
          }                                                                              \
        } else {                                                                         \
          const f16* ap_ = A1 + (k_ - 1024);                                             \
          _Pragma("unroll") for (int rf = 0; rf < 4; ++rf)                               \
            GLD_C(af[(kk) & 3][rf], ap_ + (size_t)(rf * 16 + l15) * 1024);               \
        }                                                                                \
      }
#define MF1(kk)                                                                          \
      { _Pragma("unroll") for (int rf = 0; rf < 4; ++rf) {                               \
          acc[rf][0] = MFMA16(af[(kk) & 3][rf], wreg[kk][0], acc[rf][0]);                \
          acc[rf][1] = MFMA16(af[(kk) & 3][rf], wreg[kk][1], acc[rf][1]); } }

      f32x4 acc[4][2];
#pragma unroll
      for (int i = 0; i < 4; ++i) {
        acc[i][0] = f32x4{0.f, 0.f, 0.f, 0.f};
        acc[i][1] = f32x4{0.f, 0.f, 0.f, 0.f};
      }

      ISSUE1(0) ISSUE1(1) ISSUE1(2) ISSUE1(3)
      WAITV(12) MF1(0) ISSUE1(4)
      WAITV(12) MF1(1) ISSUE1(5)
      WAITV(12) MF1(2) ISSUE1(6)
      WAITV(12) MF1(3) ISSUE1(7)
      WAITV(12) MF1(4)
      WAITV(8)  MF1(5)
      WAITV(4)  MF1(6)
      WAITV(0)  MF1(7)
#undef ISSUE1
#undef MF1

      CRED_AND_POINTWISE(hout);
    }
  }
#undef POLLG
#undef CRED_AND_POINTWISE
#undef GLD_X
#undef GLD_C
#undef WAITV
}

// ---------------- final FC ----------------
__global__ __launch_bounds__(512, 1)
void k_fc(const f16* __restrict__ h1all, const f16* __restrict__ Wfc16,
          const float* __restrict__ bfc, float* __restrict__ out) {
  const int s = blockIdx.x;
  const f16* A = h1all + (size_t)s * 65536;
  __shared__ float credf[8][64][68];

  const int w = threadIdx.x >> 6;
  const int lane = threadIdx.x & 63;
  const int l15 = lane & 15;
  const int ksub = (lane >> 4) << 3;

  f32x4 acc[4][4];
#pragma unroll
  for (int i = 0; i < 4; ++i)
#pragma unroll
    for (int j = 0; j < 4; ++j) acc[i][j] = f32x4{0.f, 0.f, 0.f, 0.f};

  const int kbeg = w * 128, kend = kbeg + 128;
  f16x8 af0[4], bf0[4], af1[4], bf1[4];

  auto LOADK = [&](int kc, f16x8(&a)[4], f16x8(&b)[4]) {
    const f16* ap = A + kc + ksub;
#pragma unroll
    for (int rf = 0; rf < 4; ++rf)
      a[rf] = *(const f16x8*)(ap + (size_t)(rf * 16 + l15) * 1024);
    const f16* bp = Wfc16 + kc + ksub;
#pragma unroll
    for (int cf = 0; cf < 4; ++cf)
      b[cf] = *(const f16x8*)(bp + (size_t)(cf * 16 + l15) * 1024);
  };

  LOADK(kbeg, af0, bf0);
  for (int kc = kbeg; kc < kend; kc += 64) {
    LOADK(kc + 32, af1, bf1);
#pragma unroll
    for (int rf = 0; rf < 4; ++rf)
#pragma unroll
      for (int cf = 0; cf < 4; ++cf) acc[rf][cf] = MFMA16(af0[rf], bf0[cf], acc[rf][cf]);
    if (kc + 64 < kend) LOADK(kc + 64, af0, bf0);
#pragma unroll
    for (int rf = 0; rf < 4; ++rf)
#pragma unroll
      for (int cf = 0; cf < 4; ++cf) acc[rf][cf] = MFMA16(af1[rf], bf1[cf], acc[rf][cf]);
  }

#pragma unroll
  for (int rf = 0; rf < 4; ++rf)
#pragma unroll
    for (int cf = 0; cf < 4; ++cf)
#pragma unroll
      for (int r = 0; r < 4; ++r)
        credf[w][rf * 16 + (lane >> 4) * 4 + r][cf * 16 + l15] = acc[rf][cf][r];

  __syncthreads();

  int m = threadIdx.x >> 3;
  int cbase = (threadIdx.x & 7) * 8;
#pragma unroll
  for (int u = 0; u < 8; ++u) {
    int col = cbase + u;
    float v = bfc[col];
#pragma unroll
    for (int ww = 0; ww < 8; ++ww) v += credf[ww][m][col];
    out[((size_t)m * 512 + s) * 64 + col] = v;
  }
}

// ---------------- host ----------------
extern "C" void kernel_launch(void* const* d_in, const int* in_sizes, int n_in,
                              void* d_out, int out_size, void* d_ws, size_t ws_size,
                              hipStream_t stream) {
  const float* x    = (const float*)d_in[0];
  const float* Wih0 = (const float*)d_in[1];
  const float* Whh0 = (const float*)d_in[2];
  const float* bih0 = (const float*)d_in[3];
  const float* bhh0 = (const float*)d_in[4];
  const float* Wih1 = (const float*)d_in[5];
  const float* Whh1 = (const float*)d_in[6];
  const float* bih1 = (const float*)d_in[7];
  const float* bhh1 = (const float*)d_in[8];
  const float* Wfc  = (const float*)d_in[9];
  const float* bfc  = (const float*)d_in[10];
  float* out = (float*)d_out;

  char* ws = (char*)d_ws;
  f16*   W0f   = (f16*)(ws + 0);           // 12,582,912
  f16*   W1f   = (f16*)(ws + 12582912);    // 16,777,216 -> 29,360,128
  f16*   Wfc16 = (f16*)(ws + 29360128);    // 131,072   -> 29,491,200
  float* b0r   = (float*)(ws + 29491200);  // 16,384    -> 29,507,584
  float* b1r   = (float*)(ws + 29507584);  // 16,384    -> 29,523,968
  f16*   x16   = (f16*)(ws + 29523968);    // 33,554,432 -> 63,078,400

  // big scheme: h0 ring 513 slots (slot 0 = zeros = h_{-1}), h1 ring 513 slots
  const size_t H0OFF = 63078400;
  const size_t SLOT = 131072;  // 64*1024*2 bytes
  const bool big = ws_size >= (size_t)197591104;

  f16 *h0ring, *h1ring;
  size_t h1off, floff;
  if (big) {
    h0ring = (f16*)(ws + H0OFF);                 // 513 * 131072 = 67,239,936
    h1off = H0OFF + 513 * SLOT;                  // 130,318,336
    h1ring = (f16*)(ws + h1off);                 // 67,239,936 -> 197,558,272
    floff = h1off + 513 * SLOT;
  } else {
    h0ring = (f16*)(ws + H0OFF);                 // 4 * 131072 = 524,288
    h1off = H0OFF + 4 * SLOT;                    // 63,602,688
    h1ring = (f16*)(ws + h1off);                 // 513 slots -> 130,842,624
    floff = h1off + 513 * SLOT;
  }
  int* flags = (int*)(ws + floff);               // 32,768
  int* gfl   = (int*)(ws + floff + 32768);       // 64

  k_conv_x<<<8192, 256, 0, stream>>>(x, x16);
  k_conv_wfrag<<<12288, 64, 0, stream>>>(Wih0, Whh0, W0f, 512, 6, 192);
  k_conv_wfrag<<<16384, 64, 0, stream>>>(Wih1, Whh1, W1f, 1024, 8, 256);
  k_conv_bias<<<64, 64, 0, stream>>>(bih0, bhh0, b0r);
  k_conv_bias<<<64, 64, 0, stream>>>(bih1, bhh1, b1r);
  k_conv_wfc<<<256, 256, 0, stream>>>(Wfc, Wfc16);
  // zero h_{-1} slots + flags every launch (graph-replay determinism)
  if (big) {
    hipMemsetAsync(ws + H0OFF, 0, SLOT, stream);           // h0_{-1}
  } else {
    hipMemsetAsync(ws + H0OFF, 0, 4 * SLOT, stream);       // whole h0 ring4
  }
  hipMemsetAsync(ws + h1off, 0, SLOT, stream);             // h1_{-1}
  hipMemsetAsync(ws + floff, 0, 32768 + 64, stream);       // flags + gflags

  {
    const f16* x16c = x16; const f16* W0fc = W0f; const float* b0rc = b0r;
    const f16* W1fc = W1f; const float* b1rc = b1r;
    f16 *p0 = h0ring, *p1 = h1ring;
    int* fl = flags; int* gf = gfl;
    void* kargs[] = { &x16c, &W0fc, &b0rc, &W1fc, &b1rc, &p0, &p1, &fl, &gf };
    if (big)
      hipLaunchCooperativeKernel((void*)(&k_persist<1>), dim3(256), dim3(512), kargs, 0, stream);
    else
      hipLaunchCooperativeKernel((void*)(&k_persist<0>), dim3(256), dim3(512), kargs, 0, stream);
  }

  // h1all = h1 ring slots 1..512
  k_fc<<<512, 512, 0, stream>>>(h1ring + 65536, Wfc16, bfc, out);
}

// Round 10
// 4775.377 us; speedup vs baseline: 1.3006x; 1.2049x over previous
//
#include <hip/hip_runtime.h>
#include <stdint.h>

typedef _Float16 f16;
typedef _Float16 f16x8 __attribute__((ext_vector_type(8)));
typedef float f32x4 __attribute__((ext_vector_type(4)));

#define MFMA16(a, b, c) __builtin_amdgcn_mfma_f32_16x16x32_f16((a), (b), (c), 0, 0, 0)

// Sizes: B=64, S=512, I=512, H=1024, 4H=4096, O=64

// ---------------- prep kernels ----------------

__global__ void k_conv_x(const float* __restrict__ x, f16* __restrict__ x16) {
  int i = blockIdx.x * 256 + threadIdx.x;
  int o = i * 8;
  int s = o >> 15, b = (o >> 9) & 63, c = o & 511;
  const float* src = x + (size_t)b * 262144 + (size_t)s * 512 + c;
  float4 v0 = *(const float4*)(src);
  float4 v1 = *(const float4*)(src + 4);
  union { f16 h[8]; f16x8 v; } t;
  t.h[0] = (f16)v0.x; t.h[1] = (f16)v0.y; t.h[2] = (f16)v0.z; t.h[3] = (f16)v0.w;
  t.h[4] = (f16)v1.x; t.h[5] = (f16)v1.y; t.h[6] = (f16)v1.z; t.h[7] = (f16)v1.w;
  *(f16x8*)(x16 + o) = t.v;
}

// Weights -> per-(colgroup,wave,kk,cf) MFMA B-fragments, f32->f16.
// fid = ((jc*8 + w)*KK + kk)*4 + cf. Lane holds W[c][k..k+7]:
//   slab col c = cf*16 + (lane&15) -> gate row g = (c>>4)*1024 + jc*16 + (c&15)
//   k = w*kPer + kk*32 + (lane>>4)*8
__global__ void k_conv_wfrag(const float* __restrict__ Wih, const float* __restrict__ Whh,
                             f16* __restrict__ Wf, int KI, int KK, int kPer) {
  int fid = blockIdx.x;
  int lane = threadIdx.x;
  int cf = fid & 3; int rest = fid >> 2;
  int kk = rest % KK; rest /= KK; int w = rest & 7; int jc = rest >> 3;
  int c = cf * 16 + (lane & 15);
  int g = (c >> 4) * 1024 + jc * 16 + (c & 15);
  int k = w * kPer + kk * 32 + ((lane >> 4) << 3);
  const float* src = (k < KI) ? (Wih + (size_t)g * KI + k)
                              : (Whh + (size_t)g * 1024 + (k - KI));
  union { f16 h[8]; f16x8 v; } t;
#pragma unroll
  for (int i = 0; i < 8; ++i) t.h[i] = (f16)src[i];
  *(f16x8*)(Wf + ((size_t)fid * 64 + lane) * 8) = t.v;
}

__global__ void k_conv_bias(const float* __restrict__ bih, const float* __restrict__ bhh,
                            float* __restrict__ br) {
  int d = blockIdx.x * 64 + threadIdx.x;  // 4096: d = jc*64 + c
  int jc = d >> 6, c = d & 63;
  int g = (c >> 4) * 1024 + jc * 16 + (c & 15);
  br[d] = bih[g] + bhh[g];
}

__global__ void k_conv_wfc(const float* __restrict__ Wfc, f16* __restrict__ Wfc16) {
  int i = blockIdx.x * 256 + threadIdx.x;
  Wfc16[i] = (f16)Wfc[i];
}

// ---------------- persistent pipelined LSTM ----------------
// 256 blocks x 512 threads, cooperative. layer = bid>>7; sub = bid&127;
// rh = sub>>6 (batch-row half, 32 rows), jc = sub&63 (16 h-cols = 64 gate-cols).
// M-split halves per-block A reads (128KB vs 256KB) -> chip h-broadcast
// 24 MB/step (was 48). Weights in VGPRs (L1: 128 VGPR/lane).
// Sync: BYTE flags packed in one 256B region (128B per layer). Producers
// store 1 byte (sc0sc1); wave 0 polls ALL 256 flags with one dword/lane
// load (2 lines/iter). Single hop (no aggregator). Wrap-safe int8 compare.
// h rings: depth 4, bypass sc0sc1 reads (r7 scheme, best measured).
__global__ __launch_bounds__(512, 2)
void k_persist(const f16* __restrict__ x16,
               const f16* __restrict__ W0f, const float* __restrict__ b0r,
               const f16* __restrict__ W1f, const float* __restrict__ b1r,
               f16* __restrict__ h0buf, f16* __restrict__ h1buf,
               f16* __restrict__ h1all, unsigned char* flags8) {
  const int layer = blockIdx.x >> 7;
  const int sub = blockIdx.x & 127;
  const int rh = sub >> 6, jc = sub & 63;

  __shared__ float cred[8][32][69];

  unsigned char* myflag = flags8 + layer * 128 + sub;

  const int tid = threadIdx.x;
  const int w = tid >> 6, lane = tid & 63;
  const int l15 = lane & 15, q8 = (lane >> 4) << 3;
  const int rbase = rh * 32;
  const int m = tid >> 4, jl = tid & 15;

  const float* bias = (layer ? b1r : b0r) + jc * 64;
  const float bI = bias[jl], bF = bias[16 + jl], bG = bias[32 + jl], bO = bias[48 + jl];
  float creg = 0.f;

#define POLLG(n0v, n1v)                                                                  \
  {                                                                                      \
    if (w == 0) {                                                                        \
      int needI = (lane < 32) ? (n0v) : (n1v);                                           \
      if (needI < 0) needI = 0;                                                          \
      unsigned int nb = (unsigned int)needI & 255u;                                      \
      const unsigned int* fp_ = (const unsigned int*)flags8 + lane;                      \
      for (;;) {                                                                         \
        unsigned int v_;                                                                 \
        asm volatile("global_load_dword %0, %1, off sc0 sc1\n\ts_waitcnt vmcnt(0)"       \
                     : "=&v"(v_) : "v"(fp_) : "memory");                                 \
        unsigned int ok = (((v_ & 255u) - nb) & 255u) < 128u;                            \
        ok &= ((((v_ >> 8) & 255u) - nb) & 255u) < 128u;                                 \
        ok &= ((((v_ >> 16) & 255u) - nb) & 255u) < 128u;                                \
        ok &= ((((v_ >> 24) & 255u) - nb) & 255u) < 128u;                                \
        if (__all(ok)) break;                                                            \
        __builtin_amdgcn_s_sleep(1);                                                     \
      }                                                                                  \
    }                                                                                    \
    __syncthreads();                                                                     \
  }

#define CRED_AND_POINTWISE(HOUT, HALL)                                                   \
  {                                                                                      \
    _Pragma("unroll") for (int rf = 0; rf < 2; ++rf)                                     \
      _Pragma("unroll") for (int cf = 0; cf < 4; ++cf)                                   \
        _Pragma("unroll") for (int r = 0; r < 4; ++r)                                    \
          cred[w][rf * 16 + (lane >> 4) * 4 + r][cf * 16 + l15] = acc[rf][cf][r];        \
    __syncthreads();                                                                     \
    float ip = bI, fp = bF, gp2 = bG, op = bO;                                           \
    _Pragma("unroll") for (int ww = 0; ww < 8; ++ww) {                                   \
      ip += cred[ww][m][jl];                                                             \
      fp += cred[ww][m][16 + jl];                                                        \
      gp2 += cred[ww][m][32 + jl];                                                       \
      op += cred[ww][m][48 + jl];                                                        \
    }                                                                                    \
    float ig = 1.f / (1.f + __expf(-ip));                                                \
    float fg = 1.f / (1.f + __expf(-fp));                                                \
    float ea = __expf(-2.f * fabsf(gp2));                                                \
    float gg = copysignf((1.f - ea) / (1.f + ea), gp2);                                  \
    float og = 1.f / (1.f + __expf(-op));                                                \
    creg = fg * creg + ig * gg;                                                          \
    float eb = __expf(-2.f * fabsf(creg));                                               \
    float hval = og * copysignf((1.f - eb) / (1.f + eb), creg);                          \
    size_t idx = (size_t)(rbase + m) * 1024 + jc * 16 + jl;                              \
    union { f16 h; unsigned short s; } cv; cv.h = (f16)hval;                             \
    __hip_atomic_store((unsigned short*)((HOUT) + idx), cv.s,                            \
                       __ATOMIC_RELAXED, __HIP_MEMORY_SCOPE_AGENT);                      \
    if (HALL) ((f16*)(HALL))[idx] = cv.h;                                                \
    __syncthreads(); /* drains vmcnt(0): h store ack'd at LLC */                         \
    if (tid == 0) {                                                                      \
      unsigned int fv = (unsigned int)(t + 1) & 255u;                                    \
      asm volatile("global_store_byte %0, %1, off sc0 sc1" ::                            \
                   "v"(myflag), "v"(fv) : "memory");                                     \
    }                                                                                    \
  }

#define GLD_X(dst, addr)                                                                 \
  asm volatile("global_load_dwordx4 %0, %1, off sc0 sc1" : "=&v"(dst) : "v"(addr) : "memory")
#define GLD_C(dst, addr)                                                                 \
  asm volatile("global_load_dwordx4 %0, %1, off" : "=&v"(dst) : "v"(addr) : "memory")
#define WAITV(n)                                                                         \
  { asm volatile("s_waitcnt vmcnt(" #n ")" ::: "memory"); __builtin_amdgcn_sched_barrier(0); }

  if (layer == 0) {
    const int KK = 6;  // kPer = 192, Ktot = 1536
    f16x8 wreg[6][4];
#pragma unroll
    for (int kk = 0; kk < KK; ++kk)
#pragma unroll
      for (int cf = 0; cf < 4; ++cf)
        wreg[kk][cf] = *(const f16x8*)(W0f + ((size_t)((jc * 8 + w) * KK + kk) * 4 + cf) * 512 + lane * 8);
#pragma unroll
    for (int kk = 0; kk < KK; ++kk)
      asm volatile("" : "+v"(wreg[kk][0]), "+v"(wreg[kk][1]), "+v"(wreg[kk][2]), "+v"(wreg[kk][3]));

    const int kbeg = w * 192;
    for (int t = 0; t < 512; ++t) {
      const f16* A0x = x16 + (size_t)t * 32768;
      const f16* A1h = h0buf + (size_t)((t + 3) & 3) * 65536;  // h0_{t-1}
      f16* hout = h0buf + (size_t)(t & 3) * 65536;             // h0_t

      f16x8 af[4][2];
#define ISSUE0(kk)                                                                       \
      {                                                                                  \
        int k_ = kbeg + (kk) * 32 + q8;                                                  \
        if (k_ < 512) {                                                                  \
          const f16* ap_ = A0x + k_;                                                     \
          GLD_C(af[(kk) & 3][0], ap_ + (size_t)(rbase + l15) * 512);                     \
          GLD_C(af[(kk) & 3][1], ap_ + (size_t)(rbase + 16 + l15) * 512);                \
        } else {                                                                         \
          const f16* ap_ = A1h + (k_ - 512);                                             \
          GLD_X(af[(kk) & 3][0], ap_ + (size_t)(rbase + l15) * 1024);                    \
          GLD_X(af[(kk) & 3][1], ap_ + (size_t)(rbase + 16 + l15) * 1024);               \
        }                                                                                \
      }
#define MF0(kk)                                                                          \
      { _Pragma("unroll") for (int rf = 0; rf < 2; ++rf)                                 \
          _Pragma("unroll") for (int cf = 0; cf < 4; ++cf)                               \
            acc[rf][cf] = MFMA16(af[(kk) & 3][rf], wreg[kk][cf], acc[rf][cf]); }

      f32x4 acc[2][4];
#pragma unroll
      for (int i = 0; i < 2; ++i)
#pragma unroll
        for (int j = 0; j < 4; ++j) acc[i][j] = f32x4{0.f, 0.f, 0.f, 0.f};

      // waves 0-2: kk0-3 are pure-x (flag-independent) -> prefetch before poll
      if (w <= 2) { ISSUE0(0) ISSUE0(1) ISSUE0(2) ISSUE0(3) }
      POLLG(t, t - 3);
      if (w > 2) { ISSUE0(0) ISSUE0(1) ISSUE0(2) ISSUE0(3) }
      WAITV(6) MF0(0) ISSUE0(4)
      WAITV(6) MF0(1) ISSUE0(5)
      WAITV(6) MF0(2)
      WAITV(4) MF0(3)
      WAITV(2) MF0(4)
      WAITV(0) MF0(5)
#undef ISSUE0
#undef MF0

      CRED_AND_POINTWISE(hout, (f16*)nullptr);
    }
  } else {
    const int KK = 8;  // kPer = 256, Ktot = 2048
    f16x8 wreg[8][4];
#pragma unroll
    for (int kk = 0; kk < KK; ++kk)
#pragma unroll
      for (int cf = 0; cf < 4; ++cf)
        wreg[kk][cf] = *(const f16x8*)(W1f + ((size_t)((jc * 8 + w) * KK + kk) * 4 + cf) * 512 + lane * 8);
#pragma unroll
    for (int kk = 0; kk < KK; ++kk)
      asm volatile("" : "+v"(wreg[kk][0]), "+v"(wreg[kk][1]), "+v"(wreg[kk][2]), "+v"(wreg[kk][3]));

    const int kbeg = w * 256;
    for (int t = 0; t < 512; ++t) {
      const f16* A0 = h0buf + (size_t)(t & 3) * 65536;        // h0_t
      const f16* A1 = h1buf + (size_t)((t + 3) & 3) * 65536;  // h1_{t-1}
      f16* hout = h1buf + (size_t)(t & 3) * 65536;            // h1_t
      f16* hall = h1all + (size_t)t * 65536;

      POLLG(t + 1, t);

      f16x8 af[4][2];
#define ISSUE1(kk)                                                                       \
      {                                                                                  \
        int k_ = kbeg + (kk) * 32 + q8;                                                  \
        const f16* ap_ = (k_ < 1024) ? (A0 + k_) : (A1 + (k_ - 1024));                   \
        GLD_X(af[(kk) & 3][0], ap_ + (size_t)(rbase + l15) * 1024);                      \
        GLD_X(af[(kk) & 3][1], ap_ + (size_t)(rbase + 16 + l15) * 1024);                 \
      }
#define MF1(kk)                                                                          \
      { _Pragma("unroll") for (int rf = 0; rf < 2; ++rf)                                 \
          _Pragma("unroll") for (int cf = 0; cf < 4; ++cf)                               \
            acc[rf][cf] = MFMA16(af[(kk) & 3][rf], wreg[kk][cf], acc[rf][cf]); }

      f32x4 acc[2][4];
#pragma unroll
      for (int i = 0; i < 2; ++i)
#pragma unroll
        for (int j = 0; j < 4; ++j) acc[i][j] = f32x4{0.f, 0.f, 0.f, 0.f};

      ISSUE1(0) ISSUE1(1) ISSUE1(2) ISSUE1(3)
      WAITV(6) MF1(0) ISSUE1(4)
      WAITV(6) MF1(1) ISSUE1(5)
      WAITV(6) MF1(2) ISSUE1(6)
      WAITV(6) MF1(3) ISSUE1(7)
      WAITV(6) MF1(4)
      WAITV(4) MF1(5)
      WAITV(2) MF1(6)
      WAITV(0) MF1(7)
#undef ISSUE1
#undef MF1

      CRED_AND_POINTWISE(hout, hall);
    }
  }
#undef POLLG
#undef CRED_AND_POINTWISE
#undef GLD_X
#undef GLD_C
#undef WAITV
}

// ---------------- final FC ----------------
__global__ __launch_bounds__(512, 1)
void k_fc(const f16* __restrict__ h1all, const f16* __restrict__ Wfc16,
          const float* __restrict__ bfc, float* __restrict__ out) {
  const int s = blockIdx.x;
  const f16* A = h1all + (size_t)s * 65536;
  __shared__ float credf[8][64][68];

  const int w = threadIdx.x >> 6;
  const int lane = threadIdx.x & 63;
  const int l15 = lane & 15;
  const int ksub = (lane >> 4) << 3;

  f32x4 acc[4][4];
#pragma unroll
  for (int i = 0; i < 4; ++i)
#pragma unroll
    for (int j = 0; j < 4; ++j) acc[i][j] = f32x4{0.f, 0.f, 0.f, 0.f};

  const int kbeg = w * 128, kend = kbeg + 128;
  f16x8 af0[4], bf0[4], af1[4], bf1[4];

  auto LOADK = [&](int kc, f16x8(&a)[4], f16x8(&b)[4]) {
    const f16* ap = A + kc + ksub;
#pragma unroll
    for (int rf = 0; rf < 4; ++rf)
      a[rf] = *(const f16x8*)(ap + (size_t)(rf * 16 + l15) * 1024);
    const f16* bp = Wfc16 + kc + ksub;
#pragma unroll
    for (int cf = 0; cf < 4; ++cf)
      b[cf] = *(const f16x8*)(bp + (size_t)(cf * 16 + l15) * 1024);
  };

  LOADK(kbeg, af0, bf0);
  for (int kc = kbeg; kc < kend; kc += 64) {
    LOADK(kc + 32, af1, bf1);
#pragma unroll
    for (int rf = 0; rf < 4; ++rf)
#pragma unroll
      for (int cf = 0; cf < 4; ++cf) acc[rf][cf] = MFMA16(af0[rf], bf0[cf], acc[rf][cf]);
    if (kc + 64 < kend) LOADK(kc + 64, af0, bf0);
#pragma unroll
    for (int rf = 0; rf < 4; ++rf)
#pragma unroll
      for (int cf = 0; cf < 4; ++cf) acc[rf][cf] = MFMA16(af1[rf], bf1[cf], acc[rf][cf]);
  }

#pragma unroll
  for (int rf = 0; rf < 4; ++rf)
#pragma unroll
    for (int cf = 0; cf < 4; ++cf)
#pragma unroll
      for (int r = 0; r < 4; ++r)
        credf[w][rf * 16 + (lane >> 4) * 4 + r][cf * 16 + l15] = acc[rf][cf][r];

  __syncthreads();

  int m = threadIdx.x >> 3;
  int cbase = (threadIdx.x & 7) * 8;
#pragma unroll
  for (int u = 0; u < 8; ++u) {
    int col = cbase + u;
    float v = bfc[col];
#pragma unroll
    for (int ww = 0; ww < 8; ++ww) v += credf[ww][m][col];
    out[((size_t)m * 512 + s) * 64 + col] = v;
  }
}

// ---------------- host ----------------
extern "C" void kernel_launch(void* const* d_in, const int* in_sizes, int n_in,
                              void* d_out, int out_size, void* d_ws, size_t ws_size,
                              hipStream_t stream) {
  const float* x    = (const float*)d_in[0];
  const float* Wih0 = (const float*)d_in[1];
  const float* Whh0 = (const float*)d_in[2];
  const float* bih0 = (const float*)d_in[3];
  const float* bhh0 = (const float*)d_in[4];
  const float* Wih1 = (const float*)d_in[5];
  const float* Whh1 = (const float*)d_in[6];
  const float* bih1 = (const float*)d_in[7];
  const float* bhh1 = (const float*)d_in[8];
  const float* Wfc  = (const float*)d_in[9];
  const float* bfc  = (const float*)d_in[10];
  float* out = (float*)d_out;

  char* ws = (char*)d_ws;
  f16*   W0f   = (f16*)(ws + 0);           // 12,582,912
  f16*   W1f   = (f16*)(ws + 12582912);    // 16,777,216 -> 29,360,128
  f16*   Wfc16 = (f16*)(ws + 29360128);    // 131,072   -> 29,491,200
  float* b0r   = (float*)(ws + 29491200);  // 16,384    -> 29,507,584
  float* b1r   = (float*)(ws + 29507584);  // 16,384    -> 29,523,968
  f16*   x16   = (f16*)(ws + 29523968);    // 33,554,432 -> 63,078,400
  f16*   h1all = (f16*)(ws + 63078400);    // 67,108,864 -> 130,187,264
  f16*   h0buf = (f16*)(ws + 130187264);   // 524,288   -> 130,711,552
  f16*   h1buf = (f16*)(ws + 130711552);   // 524,288   -> 131,235,840
  unsigned char* flags8 = (unsigned char*)(ws + 131235840);  // 256 B

  k_conv_x<<<8192, 256, 0, stream>>>(x, x16);
  k_conv_wfrag<<<12288, 64, 0, stream>>>(Wih0, Whh0, W0f, 512, 6, 192);
  k_conv_wfrag<<<16384, 64, 0, stream>>>(Wih1, Whh1, W1f, 1024, 8, 256);
  k_conv_bias<<<64, 64, 0, stream>>>(bih0, bhh0, b0r);
  k_conv_bias<<<64, 64, 0, stream>>>(bih1, bhh1, b1r);
  k_conv_wfc<<<256, 256, 0, stream>>>(Wfc, Wfc16);
  // zero h rings + flags every launch (graph-replay determinism)
  hipMemsetAsync(ws + 130187264, 0, 524288 * 2 + 256, stream);

  {
    const f16* x16c = x16; const f16* W0fc = W0f; const float* b0rc = b0r;
    const f16* W1fc = W1f; const float* b1rc = b1r;
    f16 *p0 = h0buf, *p1 = h1buf, *ph = h1all;
    unsigned char* fl = flags8;
    void* kargs[] = { &x16c, &W0fc, &b0rc, &W1fc, &b1rc, &p0, &p1, &ph, &fl };
    hipLaunchCooperativeKernel((void*)k_persist, dim3(256), dim3(512), kargs, 0, stream);
  }

  k_fc<<<512, 512, 0, stream>>>(h1all, Wfc16, bfc, out);
}

// Round 11
// 4680.952 us; speedup vs baseline: 1.3269x; 1.0202x over previous
//
#include <hip/hip_runtime.h>
#include <stdint.h>

typedef _Float16 f16;
typedef _Float16 f16x8 __attribute__((ext_vector_type(8)));
typedef float f32x4 __attribute__((ext_vector_type(4)));

#define MFMA16(a, b, c) __builtin_amdgcn_mfma_f32_16x16x32_f16((a), (b), (c), 0, 0, 0)

// Sizes: B=64, S=512, I=512, H=1024, 4H=4096, O=64

// ---------------- prep kernels ----------------

__global__ void k_conv_x(const float* __restrict__ x, f16* __restrict__ x16) {
  int i = blockIdx.x * 256 + threadIdx.x;
  int o = i * 8;
  int s = o >> 15, b = (o >> 9) & 63, c = o & 511;
  const float* src = x + (size_t)b * 262144 + (size_t)s * 512 + c;
  float4 v0 = *(const float4*)(src);
  float4 v1 = *(const float4*)(src + 4);
  union { f16 h[8]; f16x8 v; } t;
  t.h[0] = (f16)v0.x; t.h[1] = (f16)v0.y; t.h[2] = (f16)v0.z; t.h[3] = (f16)v0.w;
  t.h[4] = (f16)v1.x; t.h[5] = (f16)v1.y; t.h[6] = (f16)v1.z; t.h[7] = (f16)v1.w;
  *(f16x8*)(x16 + o) = t.v;
}

// Weights -> per-(colgroup,wave,kk,cf) MFMA B-fragments, f32->f16.
// fid = ((jc*8 + w)*KK + kk)*4 + cf. Lane holds W[c][k..k+7]:
//   slab col c = cf*16 + (lane&15) -> gate row g = (c>>4)*1024 + jc*16 + (c&15)
//   k = w*kPer + kk*32 + (lane>>4)*8
__global__ void k_conv_wfrag(const float* __restrict__ Wih, const float* __restrict__ Whh,
                             f16* __restrict__ Wf, int KI, int KK, int kPer) {
  int fid = blockIdx.x;
  int lane = threadIdx.x;
  int cf = fid & 3; int rest = fid >> 2;
  int kk = rest % KK; rest /= KK; int w = rest & 7; int jc = rest >> 3;
  int c = cf * 16 + (lane & 15);
  int g = (c >> 4) * 1024 + jc * 16 + (c & 15);
  int k = w * kPer + kk * 32 + ((lane >> 4) << 3);
  const float* src = (k < KI) ? (Wih + (size_t)g * KI + k)
                              : (Whh + (size_t)g * 1024 + (k - KI));
  union { f16 h[8]; f16x8 v; } t;
#pragma unroll
  for (int i = 0; i < 8; ++i) t.h[i] = (f16)src[i];
  *(f16x8*)(Wf + ((size_t)fid * 64 + lane) * 8) = t.v;
}

__global__ void k_conv_bias(const float* __restrict__ bih, const float* __restrict__ bhh,
                            float* __restrict__ br) {
  int d = blockIdx.x * 64 + threadIdx.x;  // 4096: d = jc*64 + c
  int jc = d >> 6, c = d & 63;
  int g = (c >> 4) * 1024 + jc * 16 + (c & 15);
  br[d] = bih[g] + bhh[g];
}

__global__ void k_conv_wfc(const float* __restrict__ Wfc, f16* __restrict__ Wfc16) {
  int i = blockIdx.x * 256 + threadIdx.x;
  Wfc16[i] = (f16)Wfc[i];
}

// ---------------- persistent pipelined LSTM ----------------
// 256 blocks x 512 threads, cooperative, 1 block/CU. layer = bid>>7;
// sub = bid&127; rh = sub>>6 (32-row half), jc = sub&63 (16 h-cols).
// waves_per_eu(2,2): force exactly 2 waves/SIMD -> 256 reg/lane budget so
// ALL weights stay register-resident (L1: 128 VGPR weights + af + acc fit).
// Sync: byte flags in one 256B region; wave 0 polls all with 1 dword/lane.
// h rings: depth 4, coalesced sc0sc1 bypass loads, counted-vmcnt pipeline.
__global__ __attribute__((amdgpu_flat_work_group_size(512, 512), amdgpu_waves_per_eu(2, 2)))
void k_persist(const f16* __restrict__ x16,
               const f16* __restrict__ W0f, const float* __restrict__ b0r,
               const f16* __restrict__ W1f, const float* __restrict__ b1r,
               f16* __restrict__ h0buf, f16* __restrict__ h1buf,
               f16* __restrict__ h1all, unsigned char* flags8) {
  const int layer = blockIdx.x >> 7;
  const int sub = blockIdx.x & 127;
  const int rh = sub >> 6, jc = sub & 63;

  __shared__ float cred[8][32][69];

  unsigned char* myflag = flags8 + layer * 128 + sub;

  const int tid = threadIdx.x;
  const int w = tid >> 6, lane = tid & 63;
  const int l15 = lane & 15, q8 = (lane >> 4) << 3;
  const int rbase = rh * 32;
  const int m = tid >> 4, jl = tid & 15;

  const float* bias = (layer ? b1r : b0r) + jc * 64;
  const float bI = bias[jl], bF = bias[16 + jl], bG = bias[32 + jl], bO = bias[48 + jl];
  float creg = 0.f;

#define POLLG(n0v, n1v)                                                                  \
  {                                                                                      \
    if (w == 0) {                                                                        \
      int needI = (lane < 32) ? (n0v) : (n1v);                                           \
      if (needI < 0) needI = 0;                                                          \
      unsigned int nb = (unsigned int)needI & 255u;                                      \
      const unsigned int* fp_ = (const unsigned int*)flags8 + lane;                      \
      for (;;) {                                                                         \
        unsigned int v_;                                                                 \
        asm volatile("global_load_dword %0, %1, off sc0 sc1\n\ts_waitcnt vmcnt(0)"       \
                     : "=&v"(v_) : "v"(fp_) : "memory");                                 \
        unsigned int ok = (((v_ & 255u) - nb) & 255u) < 128u;                            \
        ok &= ((((v_ >> 8) & 255u) - nb) & 255u) < 128u;                                 \
        ok &= ((((v_ >> 16) & 255u) - nb) & 255u) < 128u;                                \
        ok &= ((((v_ >> 24) & 255u) - nb) & 255u) < 128u;                                \
        if (__all(ok)) break;                                                            \
        __builtin_amdgcn_s_sleep(1);                                                     \
      }                                                                                  \
    }                                                                                    \
    __syncthreads();                                                                     \
  }

#define CRED_AND_POINTWISE(HOUT, HALL)                                                   \
  {                                                                                      \
    _Pragma("unroll") for (int rf = 0; rf < 2; ++rf)                                     \
      _Pragma("unroll") for (int cf = 0; cf < 4; ++cf)                                   \
        _Pragma("unroll") for (int r = 0; r < 4; ++r)                                    \
          cred[w][rf * 16 + (lane >> 4) * 4 + r][cf * 16 + l15] = acc[rf][cf][r];        \
    __syncthreads();                                                                     \
    float ip = bI, fp = bF, gp2 = bG, op = bO;                                           \
    _Pragma("unroll") for (int ww = 0; ww < 8; ++ww) {                                   \
      ip += cred[ww][m][jl];                                                             \
      fp += cred[ww][m][16 + jl];                                                        \
      gp2 += cred[ww][m][32 + jl];                                                       \
      op += cred[ww][m][48 + jl];                                                        \
    }                                                                                    \
    float ig = 1.f / (1.f + __expf(-ip));                                                \
    float fg = 1.f / (1.f + __expf(-fp));                                                \
    float ea = __expf(-2.f * fabsf(gp2));                                                \
    float gg = copysignf((1.f - ea) / (1.f + ea), gp2);                                  \
    float og = 1.f / (1.f + __expf(-op));                                                \
    creg = fg * creg + ig * gg;                                                          \
    float eb = __expf(-2.f * fabsf(creg));                                               \
    float hval = og * copysignf((1.f - eb) / (1.f + eb), creg);                          \
    size_t idx = (size_t)(rbase + m) * 1024 + jc * 16 + jl;                              \
    union { f16 h; unsigned short s; } cv; cv.h = (f16)hval;                             \
    __hip_atomic_store((unsigned short*)((HOUT) + idx), cv.s,                            \
                       __ATOMIC_RELAXED, __HIP_MEMORY_SCOPE_AGENT);                      \
    if (HALL) ((f16*)(HALL))[idx] = cv.h;                                                \
    __syncthreads(); /* drains vmcnt(0): h store ack'd at LLC */                         \
    if (tid == 0) {                                                                      \
      unsigned int fv = (unsigned int)(t + 1) & 255u;                                    \
      asm volatile("global_store_byte %0, %1, off sc0 sc1" ::                            \
                   "v"(myflag), "v"(fv) : "memory");                                     \
    }                                                                                    \
  }

#define GLD_X(dst, addr)                                                                 \
  asm volatile("global_load_dwordx4 %0, %1, off sc0 sc1" : "=&v"(dst) : "v"(addr) : "memory")
#define GLD_C(dst, addr)                                                                 \
  asm volatile("global_load_dwordx4 %0, %1, off" : "=&v"(dst) : "v"(addr) : "memory")
#define WAITV(n)                                                                         \
  { asm volatile("s_waitcnt vmcnt(" #n ")" ::: "memory"); __builtin_amdgcn_sched_barrier(0); }

  if (layer == 0) {
    const int KK = 6;  // kPer = 192, Ktot = 1536
    f16x8 wreg[6][4];
#pragma unroll
    for (int kk = 0; kk < KK; ++kk)
#pragma unroll
      for (int cf = 0; cf < 4; ++cf)
        wreg[kk][cf] = *(const f16x8*)(W0f + ((size_t)((jc * 8 + w) * KK + kk) * 4 + cf) * 512 + lane * 8);
#pragma unroll
    for (int kk = 0; kk < KK; ++kk)
      asm volatile("" : "+v"(wreg[kk][0]), "+v"(wreg[kk][1]), "+v"(wreg[kk][2]), "+v"(wreg[kk][3]));

    const int kbeg = w * 192;
    for (int t = 0; t < 512; ++t) {
      const f16* A0x = x16 + (size_t)t * 32768;
      const f16* A1h = h0buf + (size_t)((t + 3) & 3) * 65536;  // h0_{t-1}
      f16* hout = h0buf + (size_t)(t & 3) * 65536;             // h0_t

      f16x8 af[4][2];
#define ISSUE0(kk)                                                                       \
      {                                                                                  \
        int k_ = kbeg + (kk) * 32 + q8;                                                  \
        if (k_ < 512) {                                                                  \
          const f16* ap_ = A0x + k_;                                                     \
          GLD_C(af[(kk) & 3][0], ap_ + (size_t)(rbase + l15) * 512);                     \
          GLD_C(af[(kk) & 3][1], ap_ + (size_t)(rbase + 16 + l15) * 512);                \
        } else {                                                                         \
          const f16* ap_ = A1h + (k_ - 512);                                             \
          GLD_X(af[(kk) & 3][0], ap_ + (size_t)(rbase + l15) * 1024);                    \
          GLD_X(af[(kk) & 3][1], ap_ + (size_t)(rbase + 16 + l15) * 1024);               \
        }                                                                                \
      }
#define MF0(kk)                                                                          \
      { _Pragma("unroll") for (int rf = 0; rf < 2; ++rf)                                 \
          _Pragma("unroll") for (int cf = 0; cf < 4; ++cf)                               \
            acc[rf][cf] = MFMA16(af[(kk) & 3][rf], wreg[kk][cf], acc[rf][cf]); }

      f32x4 acc[2][4];
#pragma unroll
      for (int i = 0; i < 2; ++i)
#pragma unroll
        for (int j = 0; j < 4; ++j) acc[i][j] = f32x4{0.f, 0.f, 0.f, 0.f};

      // waves 0-2: kk0-3 are pure-x (flag-independent) -> prefetch before poll
      if (w <= 2) { ISSUE0(0) ISSUE0(1) ISSUE0(2) ISSUE0(3) }
      POLLG(t, t - 3);
      if (w > 2) { ISSUE0(0) ISSUE0(1) ISSUE0(2) ISSUE0(3) }
      WAITV(6) MF0(0) ISSUE0(4)
      WAITV(6) MF0(1) ISSUE0(5)
      WAITV(6) MF0(2)
      WAITV(4) MF0(3)
      WAITV(2) MF0(4)
      WAITV(0) MF0(5)
#undef ISSUE0
#undef MF0

      CRED_AND_POINTWISE(hout, (f16*)nullptr);
    }
  } else {
    const int KK = 8;  // kPer = 256, Ktot = 2048
    f16x8 wreg[8][4];
#pragma unroll
    for (int kk = 0; kk < KK; ++kk)
#pragma unroll
      for (int cf = 0; cf < 4; ++cf)
        wreg[kk][cf] = *(const f16x8*)(W1f + ((size_t)((jc * 8 + w) * KK + kk) * 4 + cf) * 512 + lane * 8);
#pragma unroll
    for (int kk = 0; kk < KK; ++kk)
      asm volatile("" : "+v"(wreg[kk][0]), "+v"(wreg[kk][1]), "+v"(wreg[kk][2]), "+v"(wreg[kk][3]));

    const int kbeg = w * 256;
    for (int t = 0; t < 512; ++t) {
      const f16* A0 = h0buf + (size_t)(t & 3) * 65536;        // h0_t
      const f16* A1 = h1buf + (size_t)((t + 3) & 3) * 65536;  // h1_{t-1}
      f16* hout = h1buf + (size_t)(t & 3) * 65536;            // h1_t
      f16* hall = h1all + (size_t)t * 65536;

      POLLG(t + 1, t);

      f16x8 af[4][2];
#define ISSUE1(kk)                                                                       \
      {                                                                                  \
        int k_ = kbeg + (kk) * 32 + q8;                                                  \
        const f16* ap_ = (k_ < 1024) ? (A0 + k_) : (A1 + (k_ - 1024));                   \
        GLD_X(af[(kk) & 3][0], ap_ + (size_t)(rbase + l15) * 1024);                      \
        GLD_X(af[(kk) & 3][1], ap_ + (size_t)(rbase + 16 + l15) * 1024);                 \
      }
#define MF1(kk)                                                                          \
      { _Pragma("unroll") for (int rf = 0; rf < 2; ++rf)                                 \
          _Pragma("unroll") for (int cf = 0; cf < 4; ++cf)                               \
            acc[rf][cf] = MFMA16(af[(kk) & 3][rf], wreg[kk][cf], acc[rf][cf]); }

      f32x4 acc[2][4];
#pragma unroll
      for (int i = 0; i < 2; ++i)
#pragma unroll
        for (int j = 0; j < 4; ++j) acc[i][j] = f32x4{0.f, 0.f, 0.f, 0.f};

      ISSUE1(0) ISSUE1(1) ISSUE1(2) ISSUE1(3)
      WAITV(6) MF1(0) ISSUE1(4)
      WAITV(6) MF1(1) ISSUE1(5)
      WAITV(6) MF1(2) ISSUE1(6)
      WAITV(6) MF1(3) ISSUE1(7)
      WAITV(6) MF1(4)
      WAITV(4) MF1(5)
      WAITV(2) MF1(6)
      WAITV(0) MF1(7)
#undef ISSUE1
#undef MF1

      CRED_AND_POINTWISE(hout, hall);
    }
  }
#undef POLLG
#undef CRED_AND_POINTWISE
#undef GLD_X
#undef GLD_C
#undef WAITV
}

// ---------------- final FC ----------------
__global__ __launch_bounds__(512, 1)
void k_fc(const f16* __restrict__ h1all, const f16* __restrict__ Wfc16,
          const float* __restrict__ bfc, float* __restrict__ out) {
  const int s = blockIdx.x;
  const f16* A = h1all + (size_t)s * 65536;
  __shared__ float credf[8][64][68];

  const int w = threadIdx.x >> 6;
  const int lane = threadIdx.x & 63;
  const int l15 = lane & 15;
  const int ksub = (lane >> 4) << 3;

  f32x4 acc[4][4];
#pragma unroll
  for (int i = 0; i < 4; ++i)
#pragma unroll
    for (int j = 0; j < 4; ++j) acc[i][j] = f32x4{0.f, 0.f, 0.f, 0.f};

  const int kbeg = w * 128, kend = kbeg + 128;
  f16x8 af0[4], bf0[4], af1[4], bf1[4];

  auto LOADK = [&](int kc, f16x8(&a)[4], f16x8(&b)[4]) {
    const f16* ap = A + kc + ksub;
#pragma unroll
    for (int rf = 0; rf < 4; ++rf)
      a[rf] = *(const f16x8*)(ap + (size_t)(rf * 16 + l15) * 1024);
    const f16* bp = Wfc16 + kc + ksub;
#pragma unroll
    for (int cf = 0; cf < 4; ++cf)
      b[cf] = *(const f16x8*)(bp + (size_t)(cf * 16 + l15) * 1024);
  };

  LOADK(kbeg, af0, bf0);
  for (int kc = kbeg; kc < kend; kc += 64) {
    LOADK(kc + 32, af1, bf1);
#pragma unroll
    for (int rf = 0; rf < 4; ++rf)
#pragma unroll
      for (int cf = 0; cf < 4; ++cf) acc[rf][cf] = MFMA16(af0[rf], bf0[cf], acc[rf][cf]);
    if (kc + 64 < kend) LOADK(kc + 64, af0, bf0);
#pragma unroll
    for (int rf = 0; rf < 4; ++rf)
#pragma unroll
      for (int cf = 0; cf < 4; ++cf) acc[rf][cf] = MFMA16(af1[rf], bf1[cf], acc[rf][cf]);
  }

#pragma unroll
  for (int rf = 0; rf < 4; ++rf)
#pragma unroll
    for (int cf = 0; cf < 4; ++cf)
#pragma unroll
      for (int r = 0; r < 4; ++r)
        credf[w][rf * 16 + (lane >> 4) * 4 + r][cf * 16 + l15] = acc[rf][cf][r];

  __syncthreads();

  int m = threadIdx.x >> 3;
  int cbase = (threadIdx.x & 7) * 8;
#pragma unroll
  for (int u = 0; u < 8; ++u) {
    int col = cbase + u;
    float v = bfc[col];
#pragma unroll
    for (int ww = 0; ww < 8; ++ww) v += credf[ww][m][col];
    out[((size_t)m * 512 + s) * 64 + col] = v;
  }
}

// ---------------- host ----------------
extern "C" void kernel_launch(void* const* d_in, const int* in_sizes, int n_in,
                              void* d_out, int out_size, void* d_ws, size_t ws_size,
                              hipStream_t stream) {
  const float* x    = (const float*)d_in[0];
  const float* Wih0 = (const float*)d_in[1];
  const float* Whh0 = (const float*)d_in[2];
  const float* bih0 = (const float*)d_in[3];
  const float* bhh0 = (const float*)d_in[4];
  const float* Wih1 = (const float*)d_in[5];
  const float* Whh1 = (const float*)d_in[6];
  const float* bih1 = (const float*)d_in[7];
  const float* bhh1 = (const float*)d_in[8];
  const float* Wfc  = (const float*)d_in[9];
  const float* bfc  = (const float*)d_in[10];
  float* out = (float*)d_out;

  char* ws = (char*)d_ws;
  f16*   W0f   = (f16*)(ws + 0);           // 12,582,912
  f16*   W1f   = (f16*)(ws + 12582912);    // 16,777,216 -> 29,360,128
  f16*   Wfc16 = (f16*)(ws + 29360128);    // 131,072   -> 29,491,200
  float* b0r   = (float*)(ws + 29491200);  // 16,384    -> 29,507,584
  float* b1r   = (float*)(ws + 29507584);  // 16,384    -> 29,523,968
  f16*   x16   = (f16*)(ws + 29523968);    // 33,554,432 -> 63,078,400
  f16*   h1all = (f16*)(ws + 63078400);    // 67,108,864 -> 130,187,264
  f16*   h0buf = (f16*)(ws + 130187264);   // 524,288   -> 130,711,552
  f16*   h1buf = (f16*)(ws + 130711552);   // 524,288   -> 131,235,840
  unsigned char* flags8 = (unsigned char*)(ws + 131235840);  // 256 B

  k_conv_x<<<8192, 256, 0, stream>>>(x, x16);
  k_conv_wfrag<<<12288, 64, 0, stream>>>(Wih0, Whh0, W0f, 512, 6, 192);
  k_conv_wfrag<<<16384, 64, 0, stream>>>(Wih1, Whh1, W1f, 1024, 8, 256);
  k_conv_bias<<<64, 64, 0, stream>>>(bih0, bhh0, b0r);
  k_conv_bias<<<64, 64, 0, stream>>>(bih1, bhh1, b1r);
  k_conv_wfc<<<256, 256, 0, stream>>>(Wfc, Wfc16);
  // zero h rings + flags every launch (graph-replay determinism)
  hipMemsetAsync(ws + 130187264, 0, 524288 * 2 + 256, stream);

  {
    const f16* x16c = x16; const f16* W0fc = W0f; const float* b0rc = b0r;
    const f16* W1fc = W1f; const float* b1rc = b1r;
    f16 *p0 = h0buf, *p1 = h1buf, *ph = h1all;
    unsigned char* fl = flags8;
    void* kargs[] = { &x16c, &W0fc, &b0rc, &W1fc, &b1rc, &p0, &p1, &ph, &fl };
    hipLaunchCooperativeKernel((void*)k_persist, dim3(256), dim3(512), kargs, 0, stream);
  }

  k_fc<<<512, 512, 0, stream>>>(h1all, Wfc16, bfc, out);
}